// Round 1
// baseline (459.845 us; speedup 1.0000x reference)
//
#include <hip/hip_runtime.h>
#include <hip/hip_bf16.h>
#include <stdint.h>

typedef unsigned short u16;
typedef __attribute__((ext_vector_type(4))) float f32x4;
typedef __attribute__((ext_vector_type(8))) __bf16 bf16x8;
typedef __attribute__((ext_vector_type(8))) unsigned short u16x8;

#define NB 2
#define NT 2048
#define NC 2048
#define NH 16
#define NKV 4
#define HD 128
#define NQKV 3072

__device__ __forceinline__ u16 f2bf(float f) {
  union { float f; uint32_t u; } c; c.f = f;
  uint32_t u = c.u + 0x7fffu + ((c.u >> 16) & 1u);
  return (u16)(u >> 16);
}
__device__ __forceinline__ float bf2f(u16 h) {
  union { uint32_t u; float f; } c; c.u = ((uint32_t)h) << 16;
  return c.f;
}

// global -> LDS async copy, 16B per lane. LDS dest must be the wave-uniform base;
// HW adds lane*16.
__device__ __forceinline__ void gload16(const void* g, void* lds) {
  __builtin_amdgcn_global_load_lds(
      (__attribute__((address_space(1))) void*)(uintptr_t)g,
      (__attribute__((address_space(3))) void*)(uint32_t)(uintptr_t)lds,
      16, 0, 0);
}

// ---------------- fp32 -> bf16 convert ----------------
__global__ void cvt_bf16_kernel(const float* __restrict__ in, u16* __restrict__ out, int n4) {
  int i = blockIdx.x * blockDim.x + threadIdx.x;
  if (i >= n4) return;
  float4 v = ((const float4*)in)[i];
  uint32_t lo = (uint32_t)f2bf(v.x) | ((uint32_t)f2bf(v.y) << 16);
  uint32_t hi = (uint32_t)f2bf(v.z) | ((uint32_t)f2bf(v.w) << 16);
  ((uint2*)out)[i] = make_uint2(lo, hi);
}

// ---------------- RoPE cos/sin table: tab[t*128 + i] = cos, tab[t*128+64+i] = sin ----------------
__global__ void rope_tab_kernel(float* __restrict__ tab) {
  int idx = blockIdx.x * blockDim.x + threadIdx.x;  // NT*64
  int t = idx >> 6, i = idx & 63;
  // inv_freq = 10000^(-2i/128) = exp(-2i * ln(10000)/128)
  float inv = expf(-(float)(2 * i) * (9.210340371976184f / 128.f));
  float f = (float)t * inv;
  tab[t * 128 + i] = cosf(f);
  tab[t * 128 + 64 + i] = sinf(f);
}

// ---------------- RoPE apply + head split/transpose ----------------
// qkv: [B*T][3072] bf16.  Q out: [B][H][T][128], K/V out: [B][KV][T][128]
__global__ void rope_apply_kernel(const u16* __restrict__ qkv, const float* __restrict__ tab,
                                  u16* __restrict__ Q, u16* __restrict__ K, u16* __restrict__ V) {
  int idx = blockIdx.x * blockDim.x + threadIdx.x;  // NB*NT*24*64
  int i = idx & 63;
  int rest = idx >> 6;
  int hh = rest % 24;
  int bt = rest / 24;            // b*NT + t
  int t = bt & (NT - 1);
  int b = bt >> 11;
  const u16* src_row = qkv + (long)bt * NQKV;
  float c = tab[t * 128 + i], s = tab[t * 128 + 64 + i];
  if (hh < NH) {
    const u16* sp = src_row + hh * HD;
    float x0 = bf2f(sp[i]), x1 = bf2f(sp[i + 64]);
    u16* dp = Q + ((long)(b * NH + hh) * NT + t) * HD;
    dp[i] = f2bf(x0 * c - x1 * s);
    dp[i + 64] = f2bf(x1 * c + x0 * s);
  } else if (hh < NH + NKV) {
    int kh = hh - NH;
    const u16* sp = src_row + (NH + kh) * HD;
    float x0 = bf2f(sp[i]), x1 = bf2f(sp[i + 64]);
    u16* dp = K + ((long)(b * NKV + kh) * NT + t) * HD;
    dp[i] = f2bf(x0 * c - x1 * s);
    dp[i + 64] = f2bf(x1 * c + x0 * s);
  } else {
    int vh = hh - NH - NKV;
    const u16* sp = src_row + (NH + NKV + vh) * HD;
    u16* dp = V + ((long)(b * NKV + vh) * NT + t) * HD;
    dp[i] = sp[i];
    dp[i + 64] = sp[i + 64];
  }
}

// ---------------- GEMM: C[M][N] = A[M][K] * B[N][K]^T  (both bf16 row-major, K contiguous) ----------------
template <int OUT_BF16>
__global__ __launch_bounds__(256) void gemm_bt_kernel(const u16* __restrict__ A,
                                                      const u16* __restrict__ Bm,
                                                      void* __restrict__ Cm,
                                                      int M, int N, int K) {
  __shared__ __align__(16) u16 As[128 * 32];
  __shared__ __align__(16) u16 Bs[128 * 32];
  const int tid = threadIdx.x;
  const int lane = tid & 63;
  const int wid = tid >> 6;
  const long row0 = (long)blockIdx.y * 128;
  const long col0 = (long)blockIdx.x * 128;
  const int wr = (wid >> 1) * 64;   // wave's 64x64 sub-tile
  const int wc = (wid & 1) * 64;
  const int g = lane >> 4;
  const int r = lane & 15;
  const int crow = lane >> 2;        // staging: row within 16-row chunk
  const int ccol = (lane & 3) * 8;   // staging: k offset
  const int c0 = wid * 2, c1 = wid * 2 + 1;

  f32x4 acc[4][4] = {};

  const u16* Abase0 = A + (row0 + c0 * 16 + crow) * (long)K + ccol;
  const u16* Abase1 = A + (row0 + c1 * 16 + crow) * (long)K + ccol;
  const u16* Bbase0 = Bm + (col0 + c0 * 16 + crow) * (long)K + ccol;
  const u16* Bbase1 = Bm + (col0 + c1 * 16 + crow) * (long)K + ccol;

  for (int k0 = 0; k0 < K; k0 += 32) {
    gload16(Abase0 + k0, &As[c0 * 512]);
    gload16(Abase1 + k0, &As[c1 * 512]);
    gload16(Bbase0 + k0, &Bs[c0 * 512]);
    gload16(Bbase1 + k0, &Bs[c1 * 512]);
    __syncthreads();
    bf16x8 af[4], bfr[4];
#pragma unroll
    for (int mi = 0; mi < 4; ++mi)
      af[mi] = *(const bf16x8*)&As[(wr + mi * 16 + r) * 32 + 8 * g];
#pragma unroll
    for (int ni = 0; ni < 4; ++ni)
      bfr[ni] = *(const bf16x8*)&Bs[(wc + ni * 16 + r) * 32 + 8 * g];
#pragma unroll
    for (int mi = 0; mi < 4; ++mi)
#pragma unroll
      for (int ni = 0; ni < 4; ++ni)
        acc[mi][ni] = __builtin_amdgcn_mfma_f32_16x16x32_bf16(af[mi], bfr[ni], acc[mi][ni], 0, 0, 0);
    __syncthreads();
  }
#pragma unroll
  for (int mi = 0; mi < 4; ++mi)
#pragma unroll
    for (int ni = 0; ni < 4; ++ni)
#pragma unroll
      for (int j = 0; j < 4; ++j) {
        long rr = row0 + wr + mi * 16 + g * 4 + j;   // C row = (lane>>4)*4 + reg
        long cc = col0 + wc + ni * 16 + r;           // C col = lane&15
        float v = acc[mi][ni][j];
        if (OUT_BF16) ((u16*)Cm)[rr * N + cc] = f2bf(v);
        else          ((float*)Cm)[rr * N + cc] = v;
      }
}

// ---------------- Flash attention (causal, GQA) ----------------
// Q: [B][H][T][128], K/V: [B][KV][T][128] bf16. Y out: [B][T][H*128] bf16.
// Block: 4 waves; 64 q-rows per block (16 per wave); KV tiles of 64.
__global__ __launch_bounds__(256) void attn_kernel(const u16* __restrict__ Qg,
                                                   const u16* __restrict__ Kg,
                                                   const u16* __restrict__ Vg,
                                                   const float* __restrict__ amask,
                                                   u16* __restrict__ Y) {
  __shared__ __align__(16) u16 Ks[64 * 128];    // row-major, XOR-swizzled (bank-conflict fix)
  __shared__ __align__(16) u16 Vt[128 * 64];    // transposed [d][kv], XOR-swizzled
  __shared__ __align__(16) u16 Ps[4][16 * 72];  // per-wave P tile, padded rows (16B-aligned)
  const int tid = threadIdx.x, lane = tid & 63, wid = tid >> 6;
  const int qt = blockIdx.x, h = blockIdx.y, b = blockIdx.z;
  const int kh = h >> 2;          // GQA: kv head = h / 4
  const int q0 = qt * 64;
  const int g = lane >> 4, r = lane & 15;

  // Q fragments in registers: lane holds q-row (wid*16 + r), k = kc*32 + 8g..+8
  const u16* Qrow = Qg + ((long)(b * NH + h) * NT + q0 + wid * 16 + r) * HD;
  bf16x8 qf[4];
#pragma unroll
  for (int kc = 0; kc < 4; ++kc)
    qf[kc] = *(const bf16x8*)(Qrow + kc * 32 + 8 * g);

  const u16* Kbh = Kg + (long)(b * NKV + kh) * NT * HD;
  const u16* Vbh = Vg + (long)(b * NKV + kh) * NT * HD;
  const float* am_b = amask + b * NT;

  float mrow[4] = {-INFINITY, -INFINITY, -INFINITY, -INFINITY};
  float lrow[4] = {0.f, 0.f, 0.f, 0.f};
  f32x4 o[8] = {};

  const int ntiles = qt + 1;  // causal: kv tiles 0..qt
  for (int kt = 0; kt < ntiles; ++kt) {
    const int kv0 = kt * 64;
    // ---- stage K (vector, swizzled) and V (transposed, conflict-free lane map) ----
#pragma unroll
    for (int i2 = 0; i2 < 4; ++i2) {
      int cc = tid + 256 * i2;
      int kv = cc >> 4;
      int d0 = (cc & 15) * 8;
      u16x8 kvec = *(const u16x8*)(Kbh + (long)(kv0 + kv) * HD + d0);
      int boff = (kv * 256 + d0 * 2) ^ ((kv & 7) << 4);
      *(u16x8*)((char*)Ks + boff) = kvec;

      int vkv = tid & 63;
      int vd0 = ((tid >> 6) + 4 * i2) * 8;
      u16x8 vvec = *(const u16x8*)(Vbh + (long)(kv0 + vkv) * HD + vd0);
#pragma unroll
      for (int e = 0; e < 8; ++e) {
        int vb2 = (((vd0 + e) * 128) + vkv * 2) ^ (((vd0 + e) & 7) << 4);
        *(u16*)((char*)Vt + vb2) = vvec[e];
      }
    }
    __syncthreads();

    // ---- S = Q K^T : 4 col-blocks of 16 kv ----
    f32x4 s[4];
#pragma unroll
    for (int cb = 0; cb < 4; ++cb) {
      f32x4 acc = {};
      int kvr = cb * 16 + r;
      int rb = kvr * 256;
      int sw = (kvr & 7) << 4;
#pragma unroll
      for (int kc = 0; kc < 4; ++kc) {
        bf16x8 kf = *(const bf16x8*)((const char*)Ks + ((rb + (kc * 32 + 8 * g) * 2) ^ sw));
        acc = __builtin_amdgcn_mfma_f32_16x16x32_bf16(qf[kc], kf, acc, 0, 0, 0);
      }
      s[cb] = acc;  // lane holds q-rows 4g+j, kv col = cb*16 + r
    }

    // ---- scale + masks ----
    const float scale = 0.088388347648318447f;  // 1/sqrt(128)
#pragma unroll
    for (int cb = 0; cb < 4; ++cb) {
      int kvi = kv0 + cb * 16 + r;
      float addm = (1.f - am_b[kvi]) * -1e30f;
#pragma unroll
      for (int j = 0; j < 4; ++j) {
        float v = s[cb][j] * scale + addm;
        if (kt == qt) {
          int qi = q0 + wid * 16 + g * 4 + j;
          if (kvi > qi) v = -INFINITY;
        }
        s[cb][j] = v;
      }
    }

    // ---- online softmax (stats per q-row, reduced across 16-lane groups) ----
    float pfrag[4][4];
    float alpha[4];
#pragma unroll
    for (int j = 0; j < 4; ++j) {
      float mx = fmaxf(fmaxf(s[0][j], s[1][j]), fmaxf(s[2][j], s[3][j]));
#pragma unroll
      for (int off = 8; off > 0; off >>= 1)
        mx = fmaxf(mx, __shfl_xor(mx, off, 16));
      float mnew = fmaxf(mrow[j], mx);
      alpha[j] = __expf(mrow[j] - mnew);
      mrow[j] = mnew;
      float sum = 0.f;
#pragma unroll
      for (int cb = 0; cb < 4; ++cb) {
        float pv = __expf(s[cb][j] - mnew);
        pfrag[cb][j] = pv;
        sum += pv;
      }
#pragma unroll
      for (int off = 8; off > 0; off >>= 1)
        sum += __shfl_xor(sum, off, 16);
      lrow[j] = lrow[j] * alpha[j] + sum;
    }
#pragma unroll
    for (int nb = 0; nb < 8; ++nb) {
      o[nb][0] *= alpha[0]; o[nb][1] *= alpha[1];
      o[nb][2] *= alpha[2]; o[nb][3] *= alpha[3];
    }

    // ---- P -> per-wave LDS (relayout for A-operand) ----
    u16* Pw = &Ps[wid][0];
#pragma unroll
    for (int cb = 0; cb < 4; ++cb)
#pragma unroll
      for (int j = 0; j < 4; ++j)
        Pw[(g * 4 + j) * 72 + cb * 16 + r] = f2bf(pfrag[cb][j]);
    asm volatile("s_waitcnt lgkmcnt(0)" ::: "memory");

    // ---- O += P V ----
#pragma unroll
    for (int kc2 = 0; kc2 < 2; ++kc2) {
      bf16x8 pa = *(const bf16x8*)&Pw[r * 72 + kc2 * 32 + 8 * g];
#pragma unroll
      for (int nb = 0; nb < 8; ++nb) {
        int vrow = nb * 16 + r;
        bf16x8 vb = *(const bf16x8*)((const char*)Vt +
            ((vrow * 128 + (kc2 * 32 + 8 * g) * 2) ^ ((vrow & 7) << 4)));
        o[nb] = __builtin_amdgcn_mfma_f32_16x16x32_bf16(pa, vb, o[nb], 0, 0, 0);
      }
    }
    __syncthreads();
  }

  // ---- epilogue: normalize, write Y[b][t][h*128+d] ----
  float invl[4] = {1.f / lrow[0], 1.f / lrow[1], 1.f / lrow[2], 1.f / lrow[3]};
#pragma unroll
  for (int nb = 0; nb < 8; ++nb)
#pragma unroll
    for (int j = 0; j < 4; ++j) {
      long tq = (long)b * NT + q0 + wid * 16 + g * 4 + j;
      Y[tq * NC + h * HD + nb * 16 + r] = f2bf(o[nb][j] * invl[j]);
    }
}

extern "C" void kernel_launch(void* const* d_in, const int* in_sizes, int n_in,
                              void* d_out, int out_size, void* d_ws, size_t ws_size,
                              hipStream_t stream) {
  const float* x = (const float*)d_in[0];
  const float* amask = (const float*)d_in[1];
  const float* w_qkv = (const float*)d_in[2];
  const float* w_proj = (const float*)d_in[3];

  const long MT = (long)NB * NT;  // 4096
  char* ws = (char*)d_ws;
  size_t off = 0;
  auto carve = [&](size_t bytes) -> char* {
    char* p = ws + off;
    off += (bytes + 255) & ~(size_t)255;
    return p;
  };
  u16* xb   = (u16*)carve((size_t)MT * NC * 2);       // later reused as Q
  u16* wqb  = (u16*)carve((size_t)NQKV * NC * 2);     // later reused as K,V
  u16* wpb  = (u16*)carve((size_t)NC * NC * 2);
  u16* qkvb = (u16*)carve((size_t)MT * NQKV * 2);     // later reused as Y
  float* tab = (float*)carve((size_t)NT * 128 * 4);

  u16* Qb = xb;
  u16* Kb = wqb;
  u16* Vb = wqb + (size_t)NB * NKV * NT * HD;
  u16* Yb = qkvb;

  {
    int n4 = (int)(MT * NC / 4);
    cvt_bf16_kernel<<<dim3((n4 + 255) / 256), dim3(256), 0, stream>>>(x, xb, n4);
    n4 = (int)((long)NQKV * NC / 4);
    cvt_bf16_kernel<<<dim3((n4 + 255) / 256), dim3(256), 0, stream>>>(w_qkv, wqb, n4);
    n4 = (int)((long)NC * NC / 4);
    cvt_bf16_kernel<<<dim3((n4 + 255) / 256), dim3(256), 0, stream>>>(w_proj, wpb, n4);
  }
  rope_tab_kernel<<<dim3(NT * 64 / 256), dim3(256), 0, stream>>>(tab);
  gemm_bt_kernel<1><<<dim3(NQKV / 128, MT / 128), dim3(256), 0, stream>>>(xb, wqb, qkvb, (int)MT, NQKV, NC);
  rope_apply_kernel<<<dim3(NB * NT * 24 * 64 / 256), dim3(256), 0, stream>>>(qkvb, tab, Qb, Kb, Vb);
  attn_kernel<<<dim3(NT / 64, NH, NB), dim3(256), 0, stream>>>(Qb, Kb, Vb, amask, Yb);
  gemm_bt_kernel<0><<<dim3(NC / 128, MT / 128), dim3(256), 0, stream>>>(Yb, wpb, d_out, (int)MT, NC, NC);
}

// Round 3
// 263.990 us; speedup vs baseline: 1.7419x; 1.7419x over previous
//
#include <hip/hip_runtime.h>
#include <hip/hip_bf16.h>
#include <stdint.h>

typedef unsigned short u16;
typedef __attribute__((ext_vector_type(4))) float f32x4;
typedef __attribute__((ext_vector_type(8))) __bf16 bf16x8;
typedef __attribute__((ext_vector_type(8))) unsigned short u16x8;

#define NB 2
#define NT 2048
#define NC 2048
#define NH 16
#define NKV 4
#define HD 128
#define NQKV 3072
#define NQT 32   // NT/64

__device__ __forceinline__ u16 f2bf(float f) {
  union { float f; uint32_t u; } c; c.f = f;
  uint32_t u = c.u + 0x7fffu + ((c.u >> 16) & 1u);
  return (u16)(u >> 16);
}
__device__ __forceinline__ float bf2f(u16 h) {
  union { uint32_t u; float f; } c; c.u = ((uint32_t)h) << 16;
  return c.f;
}
__device__ __forceinline__ uint32_t packbf2(float a, float b) {
  return (uint32_t)f2bf(a) | ((uint32_t)f2bf(b) << 16);
}

// global -> LDS async copy, 16B per lane. LDS dest = wave-uniform base + lane*16.
__device__ __forceinline__ void gload16(const void* g, void* lds) {
  __builtin_amdgcn_global_load_lds(
      (__attribute__((address_space(1))) void*)(uintptr_t)g,
      (__attribute__((address_space(3))) void*)(uint32_t)(uintptr_t)lds,
      16, 0, 0);
}

// ---------------- fp32 -> bf16 convert ----------------
__global__ void cvt_bf16_kernel(const float* __restrict__ in, u16* __restrict__ out, int n4) {
  int i = blockIdx.x * blockDim.x + threadIdx.x;
  if (i >= n4) return;
  float4 v = ((const float4*)in)[i];
  uint32_t lo = (uint32_t)f2bf(v.x) | ((uint32_t)f2bf(v.y) << 16);
  uint32_t hi = (uint32_t)f2bf(v.z) | ((uint32_t)f2bf(v.w) << 16);
  ((uint2*)out)[i] = make_uint2(lo, hi);
}

// ---------------- RoPE cos/sin table ----------------
__global__ void rope_tab_kernel(float* __restrict__ tab) {
  int idx = blockIdx.x * blockDim.x + threadIdx.x;  // NT*64
  int t = idx >> 6, i = idx & 63;
  float inv = expf(-(float)(2 * i) * (9.210340371976184f / 128.f));
  float f = (float)t * inv;
  tab[t * 128 + i] = cosf(f);
  tab[t * 128 + 64 + i] = sinf(f);
}

// ---------------- RoPE apply + head split/transpose ----------------
__global__ void rope_apply_kernel(const u16* __restrict__ qkv, const float* __restrict__ tab,
                                  u16* __restrict__ Q, u16* __restrict__ K, u16* __restrict__ V) {
  int idx = blockIdx.x * blockDim.x + threadIdx.x;  // NB*NT*24*64
  int i = idx & 63;
  int rest = idx >> 6;
  int hh = rest % 24;
  int bt = rest / 24;
  int t = bt & (NT - 1);
  int b = bt >> 11;
  const u16* src_row = qkv + (long)bt * NQKV;
  float c = tab[t * 128 + i], s = tab[t * 128 + 64 + i];
  if (hh < NH) {
    const u16* sp = src_row + hh * HD;
    float x0 = bf2f(sp[i]), x1 = bf2f(sp[i + 64]);
    u16* dp = Q + ((long)(b * NH + hh) * NT + t) * HD;
    dp[i] = f2bf(x0 * c - x1 * s);
    dp[i + 64] = f2bf(x1 * c + x0 * s);
  } else if (hh < NH + NKV) {
    int kh = hh - NH;
    const u16* sp = src_row + (NH + kh) * HD;
    float x0 = bf2f(sp[i]), x1 = bf2f(sp[i + 64]);
    u16* dp = K + ((long)(b * NKV + kh) * NT + t) * HD;
    dp[i] = f2bf(x0 * c - x1 * s);
    dp[i + 64] = f2bf(x1 * c + x0 * s);
  } else {
    int vh = hh - NH - NKV;
    const u16* sp = src_row + (NH + NKV + vh) * HD;
    u16* dp = V + ((long)(b * NKV + vh) * NT + t) * HD;
    dp[i] = sp[i];
    dp[i + 64] = sp[i + 64];
  }
}

// ---------------- GEMM: C[M][N] = A[M][K] * B[N][K]^T ----------------
template <int OUT_BF16>
__global__ __launch_bounds__(256) void gemm_bt_kernel(const u16* __restrict__ A,
                                                      const u16* __restrict__ Bm,
                                                      void* __restrict__ Cm,
                                                      int M, int N, int K) {
  __shared__ __align__(16) u16 As[128 * 32];
  __shared__ __align__(16) u16 Bs[128 * 32];
  const int tid = threadIdx.x;
  const int lane = tid & 63;
  const int wid = tid >> 6;
  const long row0 = (long)blockIdx.y * 128;
  const long col0 = (long)blockIdx.x * 128;
  const int wr = (wid >> 1) * 64;
  const int wc = (wid & 1) * 64;
  const int g = lane >> 4;
  const int r = lane & 15;
  const int crow = lane >> 2;
  const int ccol = (lane & 3) * 8;
  const int c0 = wid * 2, c1 = wid * 2 + 1;

  f32x4 acc[4][4] = {};

  const u16* Abase0 = A + (row0 + c0 * 16 + crow) * (long)K + ccol;
  const u16* Abase1 = A + (row0 + c1 * 16 + crow) * (long)K + ccol;
  const u16* Bbase0 = Bm + (col0 + c0 * 16 + crow) * (long)K + ccol;
  const u16* Bbase1 = Bm + (col0 + c1 * 16 + crow) * (long)K + ccol;

  for (int k0 = 0; k0 < K; k0 += 32) {
    gload16(Abase0 + k0, &As[c0 * 512]);
    gload16(Abase1 + k0, &As[c1 * 512]);
    gload16(Bbase0 + k0, &Bs[c0 * 512]);
    gload16(Bbase1 + k0, &Bs[c1 * 512]);
    __syncthreads();
    bf16x8 af[4], bfr[4];
#pragma unroll
    for (int mi = 0; mi < 4; ++mi)
      af[mi] = *(const bf16x8*)&As[(wr + mi * 16 + r) * 32 + 8 * g];
#pragma unroll
    for (int ni = 0; ni < 4; ++ni)
      bfr[ni] = *(const bf16x8*)&Bs[(wc + ni * 16 + r) * 32 + 8 * g];
#pragma unroll
    for (int mi = 0; mi < 4; ++mi)
#pragma unroll
      for (int ni = 0; ni < 4; ++ni)
        acc[mi][ni] = __builtin_amdgcn_mfma_f32_16x16x32_bf16(af[mi], bfr[ni], acc[mi][ni], 0, 0, 0);
    __syncthreads();
  }
#pragma unroll
  for (int mi = 0; mi < 4; ++mi)
#pragma unroll
    for (int ni = 0; ni < 4; ++ni)
#pragma unroll
      for (int j = 0; j < 4; ++j) {
        long rr = row0 + wr + mi * 16 + g * 4 + j;
        long cc = col0 + wc + ni * 16 + r;
        float v = acc[mi][ni][j];
        if (OUT_BF16) ((u16*)Cm)[rr * N + cc] = f2bf(v);
        else          ((float*)Cm)[rr * N + cc] = v;
      }
}

// ---------------- Flash attention v2: swapped-operand, balanced, double-buffered ----------------
// Grid: (NQT/2, NH, NB), 256 threads. Block x handles q-tiles x and NQT-1-x (33 KV tiles total).
// S^T = mfma(K, Q): lane owns q = wid*16+r for stats/P/O (O computed transposed via mfma(V^T, P)).
__global__ __launch_bounds__(256) void attn_kernel(const u16* __restrict__ Qg,
                                                   const u16* __restrict__ Kg,
                                                   const u16* __restrict__ Vg,
                                                   const float* __restrict__ amask,
                                                   u16* __restrict__ Y) {
  __shared__ __align__(16) u16 Ks[2][64 * 128];   // row-major [kv][d], chunk-swizzled c^=(kv&7)
  __shared__ __align__(16) u16 Vt[2][128 * 64];   // transposed [d][kv], byte^=(d&7)<<4
  __shared__ __align__(16) u16 Ps[4][16 * 72];    // per-wave P [q=r][kv], pad 72
  const int tid = threadIdx.x, lane = tid & 63, wid = tid >> 6;
  const int g = lane >> 4, r = lane & 15;
  const int h = blockIdx.y, b = blockIdx.z;
  const int kh = h >> 2;
  const int qta = blockIdx.x, qtb = NQT - 1 - qta;

  const u16* Kbh = Kg + (long)(b * NKV + kh) * NT * HD;
  const u16* Vbh = Vg + (long)(b * NKV + kh) * NT * HD;
  const u16* Qbh = Qg + (long)(b * NH + h) * NT * HD;
  const float* am_b = amask + b * NT;
  u16* Pw = &Ps[wid][0];

  const int total = qta + 1 + qtb + 1;  // == NQT + 1 == 33, identical for every block

  int krow_l = lane >> 4;           // K stage: local row within 4-row chunk
  int kchunk = lane & 15;           // K stage: LDS 16B-chunk index (linear dest)
  auto stageK = [&](u16* dst, int kv0) {
#pragma unroll
    for (int ii = 0; ii < 4; ++ii) {
      int kvl = (wid * 4 + ii) * 4 + krow_l;
      // pre-swizzled source so that swizzled reads see linear data (rule 21)
      const u16* src = Kbh + (long)(kv0 + kvl) * HD + ((kchunk ^ (kvl & 7)) * 8);
      gload16(src, dst + (wid * 4 + ii) * 512);
    }
  };
  auto loadV = [&](u16x8* vreg, int kv0) {
#pragma unroll
    for (int i2 = 0; i2 < 4; ++i2) {
      int vd0 = (wid + 4 * i2) * 8;
      vreg[i2] = *(const u16x8*)(Vbh + (long)(kv0 + lane) * HD + vd0);
    }
  };
  auto writeV = [&](u16* dst, const u16x8* vreg) {
#pragma unroll
    for (int i2 = 0; i2 < 4; ++i2) {
      int vd0 = (wid + 4 * i2) * 8;
#pragma unroll
      for (int e = 0; e < 8; ++e) {
        int d = vd0 + e;
        int byo = (d * 128 + lane * 2) ^ ((d & 7) << 4);
        *(u16*)((char*)dst + byo) = vreg[i2][e];
      }
    }
  };
  bf16x8 qf[4];
  auto loadQ = [&](int q0) {
    const u16* Qrow = Qbh + (long)(q0 + wid * 16 + r) * HD;
#pragma unroll
    for (int kc = 0; kc < 4; ++kc)
      qf[kc] = *(const bf16x8*)(Qrow + kc * 32 + 8 * g);
  };

  // ---- prologue: stage tile 0, load Q for pass A ----
  u16x8 vreg[4];
  stageK(Ks[0], 0);
  loadV(vreg, 0);
  loadQ(qta * 64);
  writeV(Vt[0], vreg);   // compiler inserts vmcnt wait for vreg
  __syncthreads();       // drains gload_lds too

  float m = -INFINITY, l = 0.f;
  f32x4 o[8] = {};
  const float scale = 0.088388347648318447f;  // 1/sqrt(128)
  int buf = 0;

  for (int i = 0; i < total; ++i) {
    const bool passA = (i <= qta);
    const int q0 = (passA ? qta : qtb) * 64;
    const int kt = passA ? i : i - qta - 1;
    const int kv0 = kt * 64;
    const bool diag = (i == qta) || (i == total - 1);
    const int qi = q0 + wid * 16 + r;  // this lane's q row

    // ---- stage next tile (K async into other buf; V into regs) ----
    if (i + 1 < total) {
      const int ktn = (i + 1 <= qta) ? i + 1 : i - qta;  // next step's kv tile
      stageK(Ks[buf ^ 1], ktn * 64);
      loadV(vreg, ktn * 64);
    }

    const u16* Ksb = Ks[buf];
    const u16* Vtb = Vt[buf];

    // ---- S^T = mfma(K, Q): lane owns S[q=qi][kv = kv0 + cb*16 + 4g + jj] ----
    f32x4 s[4];
#pragma unroll
    for (int cb = 0; cb < 4; ++cb) {
      f32x4 acc = {};
      int row = cb * 16 + r;
      int swz = (r & 7) << 4;
#pragma unroll
      for (int kc = 0; kc < 4; ++kc) {
        bf16x8 kf = *(const bf16x8*)((const char*)Ksb + ((row * 256 + (kc * 32 + 8 * g) * 2) ^ swz));
        acc = __builtin_amdgcn_mfma_f32_16x16x32_bf16(kf, qf[kc], acc, 0, 0, 0);
      }
      s[cb] = acc;
    }

    // ---- scale + causal (diag tiles only) ----
#pragma unroll
    for (int cb = 0; cb < 4; ++cb)
#pragma unroll
      for (int jj = 0; jj < 4; ++jj) {
        float v = s[cb][jj] * scale;
        if (diag) {
          int kvi = kv0 + cb * 16 + 4 * g + jj;
          if (kvi > qi) v = -INFINITY;
        }
        s[cb][jj] = v;
      }

    // ---- online softmax: scalar max tree + 2 shfl (lanes r,r+16,r+32,r+48 share q) ----
    float mx = s[0][0];
#pragma unroll
    for (int cb = 0; cb < 4; ++cb)
#pragma unroll
      for (int jj = 0; jj < 4; ++jj) mx = fmaxf(mx, s[cb][jj]);
    mx = fmaxf(mx, __shfl_xor(mx, 16));
    mx = fmaxf(mx, __shfl_xor(mx, 32));
    float mnew = fmaxf(m, mx);
    float alpha = __expf(m - mnew);
    m = mnew;

    float4 amv[4];
#pragma unroll
    for (int cb = 0; cb < 4; ++cb)
      amv[cb] = *(const float4*)(am_b + kv0 + cb * 16 + 4 * g);

    float p[4][4];
    float lsum = 0.f;
#pragma unroll
    for (int cb = 0; cb < 4; ++cb)
#pragma unroll
      for (int jj = 0; jj < 4; ++jj) {
        float pv = __expf(s[cb][jj] - mnew) * (&amv[cb].x)[jj];  // multiplicative mask (exact for 0/1)
        p[cb][jj] = pv;
        lsum += pv;
      }
    lsum += __shfl_xor(lsum, 16);
    lsum += __shfl_xor(lsum, 32);
    l = l * alpha + lsum;
#pragma unroll
    for (int nb = 0; nb < 8; ++nb) {
      o[nb][0] *= alpha; o[nb][1] *= alpha; o[nb][2] *= alpha; o[nb][3] *= alpha;
    }

    // ---- P -> per-wave LDS (row q=r), 4x ds_write_b64 ----
#pragma unroll
    for (int cb = 0; cb < 4; ++cb)
      *(uint2*)((char*)Pw + 144 * r + 32 * cb + 8 * g) =
          make_uint2(packbf2(p[cb][0], p[cb][1]), packbf2(p[cb][2], p[cb][3]));
    asm volatile("s_waitcnt lgkmcnt(0)" ::: "memory");
    __builtin_amdgcn_sched_barrier(0);

    // ---- O^T += mfma(V^T, P): lane owns O[q=qi][d = nb*16 + 4g + jj] ----
#pragma unroll
    for (int kc = 0; kc < 2; ++kc) {
      bf16x8 pb = *(const bf16x8*)((const char*)Pw + 144 * r + kc * 64 + 16 * g);
#pragma unroll
      for (int nb = 0; nb < 8; ++nb) {
        int d = nb * 16 + r;
        bf16x8 va = *(const bf16x8*)((const char*)Vtb +
            ((d * 128 + (kc * 32 + 8 * g) * 2) ^ ((d & 7) << 4)));
        o[nb] = __builtin_amdgcn_mfma_f32_16x16x32_bf16(va, pb, o[nb], 0, 0, 0);
      }
    }

    // ---- pass epilogue ----
    if (diag) {
      float invl = 1.f / l;
      u16* Yrow = Y + ((long)b * NT + qi) * NC + h * HD;
#pragma unroll
      for (int nb = 0; nb < 8; ++nb)
        *(uint2*)(Yrow + nb * 16 + 4 * g) =
            make_uint2(packbf2(o[nb][0] * invl, o[nb][1] * invl),
                       packbf2(o[nb][2] * invl, o[nb][3] * invl));
      if (i == qta) {  // reset for pass B
        m = -INFINITY; l = 0.f;
#pragma unroll
        for (int nb = 0; nb < 8; ++nb) o[nb] = f32x4{};
        loadQ(qtb * 64);
      }
    }

    // ---- commit next tile's V to LDS, swap ----
    if (i + 1 < total) writeV(Vt[buf ^ 1], vreg);
    __syncthreads();
    buf ^= 1;
  }
}

extern "C" void kernel_launch(void* const* d_in, const int* in_sizes, int n_in,
                              void* d_out, int out_size, void* d_ws, size_t ws_size,
                              hipStream_t stream) {
  const float* x = (const float*)d_in[0];
  const float* amask = (const float*)d_in[1];
  const float* w_qkv = (const float*)d_in[2];
  const float* w_proj = (const float*)d_in[3];

  const long MT = (long)NB * NT;  // 4096
  char* ws = (char*)d_ws;
  size_t off = 0;
  auto carve = [&](size_t bytes) -> char* {
    char* p = ws + off;
    off += (bytes + 255) & ~(size_t)255;
    return p;
  };
  u16* xb   = (u16*)carve((size_t)MT * NC * 2);       // reused as Q
  u16* wqb  = (u16*)carve((size_t)NQKV * NC * 2);     // reused as K,V
  u16* wpb  = (u16*)carve((size_t)NC * NC * 2);
  u16* qkvb = (u16*)carve((size_t)MT * NQKV * 2);     // reused as Y
  float* tab = (float*)carve((size_t)NT * 128 * 4);

  u16* Qb = xb;
  u16* Kb = wqb;
  u16* Vb = wqb + (size_t)NB * NKV * NT * HD;
  u16* Yb = qkvb;

  {
    int n4 = (int)(MT * NC / 4);
    cvt_bf16_kernel<<<dim3((n4 + 255) / 256), dim3(256), 0, stream>>>(x, xb, n4);
    n4 = (int)((long)NQKV * NC / 4);
    cvt_bf16_kernel<<<dim3((n4 + 255) / 256), dim3(256), 0, stream>>>(w_qkv, wqb, n4);
    n4 = (int)((long)NC * NC / 4);
    cvt_bf16_kernel<<<dim3((n4 + 255) / 256), dim3(256), 0, stream>>>(w_proj, wpb, n4);
  }
  rope_tab_kernel<<<dim3(NT * 64 / 256), dim3(256), 0, stream>>>(tab);
  gemm_bt_kernel<1><<<dim3(NQKV / 128, MT / 128), dim3(256), 0, stream>>>(xb, wqb, qkvb, (int)MT, NQKV, NC);
  rope_apply_kernel<<<dim3(NB * NT * 24 * 64 / 256), dim3(256), 0, stream>>>(qkvb, tab, Qb, Kb, Vb);
  attn_kernel<<<dim3(NQT / 2, NH, NB), dim3(256), 0, stream>>>(Qb, Kb, Vb, amask, Yb);
  gemm_bt_kernel<0><<<dim3(NC / 128, MT / 128), dim3(256), 0, stream>>>(Yb, wpb, d_out, (int)MT, NC, NC);
}

// Round 5
// 247.793 us; speedup vs baseline: 1.8558x; 1.0654x over previous
//
#include <hip/hip_runtime.h>
#include <hip/hip_bf16.h>
#include <stdint.h>

typedef unsigned short u16;
typedef __attribute__((ext_vector_type(4))) float f32x4;
typedef __attribute__((ext_vector_type(8))) __bf16 bf16x8;
typedef __attribute__((ext_vector_type(8))) unsigned short u16x8;

#define NB 2
#define NT 2048
#define NC 2048
#define NH 16
#define NKV 4
#define HD 128
#define NQKV 3072
#define NQT 32   // NT/64

__device__ __forceinline__ u16 f2bf(float f) {
  union { float f; uint32_t u; } c; c.f = f;
  uint32_t u = c.u + 0x7fffu + ((c.u >> 16) & 1u);
  return (u16)(u >> 16);
}
__device__ __forceinline__ float bf2f(u16 h) {
  union { uint32_t u; float f; } c; c.u = ((uint32_t)h) << 16;
  return c.f;
}
__device__ __forceinline__ uint32_t packbf2(float a, float b) {
  return (uint32_t)f2bf(a) | ((uint32_t)f2bf(b) << 16);
}

// global -> LDS async copy, 16B per lane. LDS dest = wave-uniform base + lane*16.
__device__ __forceinline__ void gload16(const void* g, void* lds) {
  __builtin_amdgcn_global_load_lds(
      (__attribute__((address_space(1))) void*)(uintptr_t)g,
      (__attribute__((address_space(3))) void*)(uint32_t)(uintptr_t)lds,
      16, 0, 0);
}

// ---------------- fp32 -> bf16 convert ----------------
__global__ void cvt_bf16_kernel(const float* __restrict__ in, u16* __restrict__ out, int n4) {
  int i = blockIdx.x * blockDim.x + threadIdx.x;
  if (i >= n4) return;
  float4 v = ((const float4*)in)[i];
  uint32_t lo = (uint32_t)f2bf(v.x) | ((uint32_t)f2bf(v.y) << 16);
  uint32_t hi = (uint32_t)f2bf(v.z) | ((uint32_t)f2bf(v.w) << 16);
  ((uint2*)out)[i] = make_uint2(lo, hi);
}

// ---------------- RoPE cos/sin table ----------------
__global__ void rope_tab_kernel(float* __restrict__ tab) {
  int idx = blockIdx.x * blockDim.x + threadIdx.x;  // NT*64
  int t = idx >> 6, i = idx & 63;
  float inv = expf(-(float)(2 * i) * (9.210340371976184f / 128.f));
  float f = (float)t * inv;
  tab[t * 128 + i] = cosf(f);
  tab[t * 128 + 64 + i] = sinf(f);
}

// ---------------- RoPE apply + head split/transpose (Q and K only) ----------------
__global__ void rope_apply_kernel(const u16* __restrict__ qkv, const float* __restrict__ tab,
                                  u16* __restrict__ Q, u16* __restrict__ K) {
  int idx = blockIdx.x * blockDim.x + threadIdx.x;  // NB*NT*20*64
  int i = idx & 63;
  int rest = idx >> 6;
  int hh = rest % 20;
  int bt = rest / 20;
  int t = bt & (NT - 1);
  int b = bt >> 11;
  const u16* src_row = qkv + (long)bt * NQKV;
  float c = tab[t * 128 + i], s = tab[t * 128 + 64 + i];
  if (hh < NH) {
    const u16* sp = src_row + hh * HD;
    float x0 = bf2f(sp[i]), x1 = bf2f(sp[i + 64]);
    u16* dp = Q + ((long)(b * NH + hh) * NT + t) * HD;
    dp[i] = f2bf(x0 * c - x1 * s);
    dp[i + 64] = f2bf(x1 * c + x0 * s);
  } else {
    int kh = hh - NH;
    const u16* sp = src_row + (NH + kh) * HD;
    float x0 = bf2f(sp[i]), x1 = bf2f(sp[i + 64]);
    u16* dp = K + ((long)(b * NKV + kh) * NT + t) * HD;
    dp[i] = f2bf(x0 * c - x1 * s);
    dp[i + 64] = f2bf(x1 * c + x0 * s);
  }
}

// ---------------- V transpose: qkv[bt][2560 + kh*128 + d] -> Vt[b][kh][d][t] ----------------
// 64t x 64d LDS tiles, coalesced both sides. Grid: (NT/64 * 2, NB*NKV), 256 threads.
__global__ void vtrans_kernel(const u16* __restrict__ qkv, u16* __restrict__ Vt) {
  __shared__ u16 tile[64][72];
  const int t0 = (blockIdx.x >> 1) * 64;
  const int d0 = (blockIdx.x & 1) * 64;
  const int bkh = blockIdx.y;                 // b*NKV + kh
  const int tid = threadIdx.x;
  const int tr = tid >> 2;
  const int tc = (tid & 3) * 16;
  const u16* src = qkv + ((long)((bkh >> 2) * NT) + t0 + tr) * NQKV +
                   (NH + NKV) * HD + (bkh & 3) * HD + d0 + tc;
  uint4 v0 = *(const uint4*)(src);
  uint4 v1 = *(const uint4*)(src + 8);
  *(uint4*)&tile[tr][tc] = v0;
  *(uint4*)&tile[tr][tc + 8] = v1;
  __syncthreads();
  const int dr = tid >> 2;
  const int tcc = (tid & 3) * 16;
  uint32_t pk[8];
#pragma unroll
  for (int e = 0; e < 8; ++e) {
    u16 a = tile[tcc + 2 * e][dr];
    u16 bq = tile[tcc + 2 * e + 1][dr];
    pk[e] = (uint32_t)a | ((uint32_t)bq << 16);
  }
  u16* dst = Vt + ((long)bkh * HD + d0 + dr) * NT + t0 + tcc;
  *(uint4*)(dst) = *(uint4*)&pk[0];
  *(uint4*)(dst + 8) = *(uint4*)&pk[4];
}

// ---------------- GEMM: C[M][N] = A[M][K] * B[N][K]^T ----------------
template <int OUT_BF16>
__global__ __launch_bounds__(256) void gemm_bt_kernel(const u16* __restrict__ A,
                                                      const u16* __restrict__ Bm,
                                                      void* __restrict__ Cm,
                                                      int M, int N, int K) {
  __shared__ __align__(16) u16 As[128 * 32];
  __shared__ __align__(16) u16 Bs[128 * 32];
  const int tid = threadIdx.x;
  const int lane = tid & 63;
  const int wid = tid >> 6;
  const long row0 = (long)blockIdx.y * 128;
  const long col0 = (long)blockIdx.x * 128;
  const int wr = (wid >> 1) * 64;
  const int wc = (wid & 1) * 64;
  const int g = lane >> 4;
  const int r = lane & 15;
  const int crow = lane >> 2;
  const int ccol = (lane & 3) * 8;
  const int c0 = wid * 2, c1 = wid * 2 + 1;

  f32x4 acc[4][4] = {};

  const u16* Abase0 = A + (row0 + c0 * 16 + crow) * (long)K + ccol;
  const u16* Abase1 = A + (row0 + c1 * 16 + crow) * (long)K + ccol;
  const u16* Bbase0 = Bm + (col0 + c0 * 16 + crow) * (long)K + ccol;
  const u16* Bbase1 = Bm + (col0 + c1 * 16 + crow) * (long)K + ccol;

  for (int k0 = 0; k0 < K; k0 += 32) {
    gload16(Abase0 + k0, &As[c0 * 512]);
    gload16(Abase1 + k0, &As[c1 * 512]);
    gload16(Bbase0 + k0, &Bs[c0 * 512]);
    gload16(Bbase1 + k0, &Bs[c1 * 512]);
    __syncthreads();
    bf16x8 af[4], bfr[4];
#pragma unroll
    for (int mi = 0; mi < 4; ++mi)
      af[mi] = *(const bf16x8*)&As[(wr + mi * 16 + r) * 32 + 8 * g];
#pragma unroll
    for (int ni = 0; ni < 4; ++ni)
      bfr[ni] = *(const bf16x8*)&Bs[(wc + ni * 16 + r) * 32 + 8 * g];
#pragma unroll
    for (int mi = 0; mi < 4; ++mi)
#pragma unroll
      for (int ni = 0; ni < 4; ++ni)
        acc[mi][ni] = __builtin_amdgcn_mfma_f32_16x16x32_bf16(af[mi], bfr[ni], acc[mi][ni], 0, 0, 0);
    __syncthreads();
  }
#pragma unroll
  for (int mi = 0; mi < 4; ++mi)
#pragma unroll
    for (int ni = 0; ni < 4; ++ni)
#pragma unroll
      for (int j = 0; j < 4; ++j) {
        long rr = row0 + wr + mi * 16 + g * 4 + j;
        long cc = col0 + wc + ni * 16 + r;
        float v = acc[mi][ni][j];
        if (OUT_BF16) ((u16*)Cm)[rr * N + cc] = f2bf(v);
        else          ((float*)Cm)[rr * N + cc] = v;
      }
}

// ---------------- Flash attention v4: pre-transposed V, all-gload staging ----------------
// Grid: (NQT/2, NH, NB), 256 threads. Block x handles q-tiles x and NQT-1-x.
// K LDS [kv][128] rows 256B, Vt LDS [d][64] rows 128B; both staged via global_load_lds
// with pre-swizzled source (read swizzle: byte ^= (row&7)<<4).
__global__ __launch_bounds__(256) void attn_kernel(const u16* __restrict__ Qg,
                                                   const u16* __restrict__ Kg,
                                                   const u16* __restrict__ Vtg,
                                                   const float* __restrict__ amask,
                                                   u16* __restrict__ Y) {
  __shared__ __align__(16) u16 Ks[2][64 * 128];
  __shared__ __align__(16) u16 Vt[2][128 * 64];
  __shared__ __align__(16) u16 Ps[4][16 * 72];
  const int tid = threadIdx.x, lane = tid & 63, wid = tid >> 6;
  const int g = lane >> 4, r = lane & 15;
  const int h = blockIdx.y, b = blockIdx.z;
  const int kh = h >> 2;
  const int qta = blockIdx.x, qtb = NQT - 1 - qta;

  const u16* Kbh = Kg + (long)(b * NKV + kh) * NT * HD;
  const u16* Vtbh = Vtg + (long)(b * NKV + kh) * HD * NT;  // [d][t]
  const u16* Qbh = Qg + (long)(b * NH + h) * NT * HD;
  const float* am_b = amask + b * NT;
  u16* Pw = &Ps[wid][0];

  const int total = qta + 1 + qtb + 1;  // == NQT + 1 == 33

  // ---- K staging: linear LDS dest, inverse-swizzled global source ----
  const int krow_l = lane >> 4;
  const int kchunk = lane & 15;
  auto stageK = [&](u16* dst, int kv0) {
#pragma unroll
    for (int ii = 0; ii < 4; ++ii) {
      int kvl = (wid * 4 + ii) * 4 + krow_l;
      const u16* src = Kbh + (long)(kv0 + kvl) * HD + ((kchunk ^ (kvl & 7)) * 8);
      gload16(src, dst + (wid * 4 + ii) * 512);
    }
  };
  // ---- Vt staging: rows d (128B each); wave covers 8 rows per gload ----
  const int vrow_l = lane >> 3;
  const int vchunk = lane & 7;
  auto stageVt = [&](u16* dst, int kv0) {
#pragma unroll
    for (int ii = 0; ii < 4; ++ii) {
      int d = (wid * 4 + ii) * 8 + vrow_l;
      const u16* src = Vtbh + (long)d * NT + kv0 + ((vchunk ^ (d & 7)) * 8);
      gload16(src, dst + (wid * 4 + ii) * 512);
    }
  };

  bf16x8 qf[4];
  auto loadQ = [&](int q0) {
    const u16* Qrow = Qbh + (long)(q0 + wid * 16 + r) * HD;
#pragma unroll
    for (int kc = 0; kc < 4; ++kc)
      qf[kc] = *(const bf16x8*)(Qrow + kc * 32 + 8 * g);
  };

  // ---- prologue ----
  stageK(Ks[0], 0);
  stageVt(Vt[0], 0);
  loadQ(qta * 64);
  __syncthreads();

  float m = -INFINITY, l = 0.f;
  f32x4 o[8] = {};
  const float scale2 = 0.12751739f;  // (1/sqrt(128)) * log2(e)
  int buf = 0;

  for (int i = 0; i < total; ++i) {
    const bool passA = (i <= qta);
    const int q0 = (passA ? qta : qtb) * 64;
    const int kt = passA ? i : i - qta - 1;
    const int kv0 = kt * 64;
    const bool diag = (i == qta) || (i == total - 1);
    const int qi = q0 + wid * 16 + r;

    if (i + 1 < total) {
      const int ktn = (i + 1 <= qta) ? i + 1 : i - qta;
      stageK(Ks[buf ^ 1], ktn * 64);
      stageVt(Vt[buf ^ 1], ktn * 64);
    }

    const u16* Ksb = Ks[buf];
    const u16* Vtb = Vt[buf];

    // ---- S^T = mfma(K, Q): lane owns S[q=qi][kv = kv0 + cb*16 + 4g + jj] ----
    f32x4 s[4];
    __builtin_amdgcn_s_setprio(1);
#pragma unroll
    for (int cb = 0; cb < 4; ++cb) {
      f32x4 acc = {};
      int row = cb * 16 + r;
      int swz = (r & 7) << 4;
#pragma unroll
      for (int kc = 0; kc < 4; ++kc) {
        bf16x8 kf = *(const bf16x8*)((const char*)Ksb + ((row * 256 + (kc * 32 + 8 * g) * 2) ^ swz));
        acc = __builtin_amdgcn_mfma_f32_16x16x32_bf16(kf, qf[kc], acc, 0, 0, 0);
      }
      s[cb] = acc;
    }
    __builtin_amdgcn_s_setprio(0);

    // ---- scale (log2 domain) + causal ----
#pragma unroll
    for (int cb = 0; cb < 4; ++cb)
#pragma unroll
      for (int jj = 0; jj < 4; ++jj) {
        float v = s[cb][jj] * scale2;
        if (diag) {
          int kvi = kv0 + cb * 16 + 4 * g + jj;
          if (kvi > qi) v = -INFINITY;
        }
        s[cb][jj] = v;
      }

    // ---- online softmax with defer-max (THR=8 in log2 units) ----
    float mx = s[0][0];
#pragma unroll
    for (int cb = 0; cb < 4; ++cb)
#pragma unroll
      for (int jj = 0; jj < 4; ++jj) mx = fmaxf(mx, s[cb][jj]);
    mx = fmaxf(mx, __shfl_xor(mx, 16));
    mx = fmaxf(mx, __shfl_xor(mx, 32));
    if (!__all(mx <= m + 8.f)) {
      float mnew = fmaxf(m, mx);
      float alpha = exp2f(m - mnew);
      m = mnew;
      l *= alpha;
#pragma unroll
      for (int nb = 0; nb < 8; ++nb) {
        o[nb][0] *= alpha; o[nb][1] *= alpha; o[nb][2] *= alpha; o[nb][3] *= alpha;
      }
    }

    float4 amv[4];
#pragma unroll
    for (int cb = 0; cb < 4; ++cb)
      amv[cb] = *(const float4*)(am_b + kv0 + cb * 16 + 4 * g);

    float p[4][4];
    float lsum = 0.f;
#pragma unroll
    for (int cb = 0; cb < 4; ++cb)
#pragma unroll
      for (int jj = 0; jj < 4; ++jj) {
        float pv = exp2f(s[cb][jj] - m) * (&amv[cb].x)[jj];
        p[cb][jj] = pv;
        lsum += pv;
      }
    lsum += __shfl_xor(lsum, 16);
    lsum += __shfl_xor(lsum, 32);
    l += lsum;

    // ---- P -> per-wave LDS (row q=r); __bf16 casts -> v_cvt_pk ----
#pragma unroll
    for (int cb = 0; cb < 4; ++cb) {
      union { __bf16 hh[4]; uint2 u; } pk;
      pk.hh[0] = (__bf16)p[cb][0]; pk.hh[1] = (__bf16)p[cb][1];
      pk.hh[2] = (__bf16)p[cb][2]; pk.hh[3] = (__bf16)p[cb][3];
      *(uint2*)((char*)Pw + 144 * r + 32 * cb + 8 * g) = pk.u;
    }
    asm volatile("s_waitcnt lgkmcnt(0)" ::: "memory");
    __builtin_amdgcn_sched_barrier(0);

    // ---- O^T += mfma(V^T, P): lane owns O[q=qi][d = nb*16 + 4g + jj] ----
    __builtin_amdgcn_s_setprio(1);
#pragma unroll
    for (int kc = 0; kc < 2; ++kc) {
      bf16x8 pb = *(const bf16x8*)((const char*)Pw + 144 * r + kc * 64 + 16 * g);
#pragma unroll
      for (int nb = 0; nb < 8; ++nb) {
        int d = nb * 16 + r;
        bf16x8 va = *(const bf16x8*)((const char*)Vtb +
            ((d * 128 + (kc * 32 + 8 * g) * 2) ^ ((d & 7) << 4)));
        o[nb] = __builtin_amdgcn_mfma_f32_16x16x32_bf16(va, pb, o[nb], 0, 0, 0);
      }
    }
    __builtin_amdgcn_s_setprio(0);

    // ---- pass epilogue ----
    if (diag) {
      float invl = 1.f / l;
      u16* Yrow = Y + ((long)b * NT + qi) * NC + h * HD;
#pragma unroll
      for (int nb = 0; nb < 8; ++nb)
        *(uint2*)(Yrow + nb * 16 + 4 * g) =
            make_uint2(packbf2(o[nb][0] * invl, o[nb][1] * invl),
                       packbf2(o[nb][2] * invl, o[nb][3] * invl));
      if (i == qta) {
        m = -INFINITY; l = 0.f;
#pragma unroll
        for (int nb = 0; nb < 8; ++nb) o[nb] = f32x4{};
        loadQ(qtb * 64);
      }
    }

    __syncthreads();
    buf ^= 1;
  }
}

extern "C" void kernel_launch(void* const* d_in, const int* in_sizes, int n_in,
                              void* d_out, int out_size, void* d_ws, size_t ws_size,
                              hipStream_t stream) {
  const float* x = (const float*)d_in[0];
  const float* amask = (const float*)d_in[1];
  const float* w_qkv = (const float*)d_in[2];
  const float* w_proj = (const float*)d_in[3];

  const long MT = (long)NB * NT;  // 4096
  char* ws = (char*)d_ws;
  size_t off = 0;
  auto carve = [&](size_t bytes) -> char* {
    char* p = ws + off;
    off += (bytes + 255) & ~(size_t)255;
    return p;
  };
  u16* xb   = (u16*)carve((size_t)MT * NC * 2);       // reused as Q
  u16* wqb  = (u16*)carve((size_t)NQKV * NC * 2);     // reused as K + Vt
  u16* wpb  = (u16*)carve((size_t)NC * NC * 2);
  u16* qkvb = (u16*)carve((size_t)MT * NQKV * 2);     // reused as Y
  float* tab = (float*)carve((size_t)NT * 128 * 4);

  u16* Qb = xb;
  u16* Kb = wqb;
  u16* Vtb = wqb + (size_t)NB * NKV * NT * HD;
  u16* Yb = qkvb;

  {
    int n4 = (int)(MT * NC / 4);
    cvt_bf16_kernel<<<dim3((n4 + 255) / 256), dim3(256), 0, stream>>>(x, xb, n4);
    n4 = (int)((long)NQKV * NC / 4);
    cvt_bf16_kernel<<<dim3((n4 + 255) / 256), dim3(256), 0, stream>>>(w_qkv, wqb, n4);
    n4 = (int)((long)NC * NC / 4);
    cvt_bf16_kernel<<<dim3((n4 + 255) / 256), dim3(256), 0, stream>>>(w_proj, wpb, n4);
  }
  rope_tab_kernel<<<dim3(NT * 64 / 256), dim3(256), 0, stream>>>(tab);
  gemm_bt_kernel<1><<<dim3(NQKV / 128, MT / 128), dim3(256), 0, stream>>>(xb, wqb, qkvb, (int)MT, NQKV, NC);
  rope_apply_kernel<<<dim3(NB * NT * 20 * 64 / 256), dim3(256), 0, stream>>>(qkvb, tab, Qb, Kb);
  vtrans_kernel<<<dim3(NT / 64 * 2, NB * NKV), dim3(256), 0, stream>>>(qkvb, Vtb);
  attn_kernel<<<dim3(NQT / 2, NH, NB), dim3(256), 0, stream>>>(Qb, Kb, Vtb, amask, Yb);
  gemm_bt_kernel<0><<<dim3(NC / 128, MT / 128), dim3(256), 0, stream>>>(Yb, wpb, d_out, (int)MT, NC, NC);
}